// Round 8
// baseline (1151.314 us; speedup 1.0000x reference)
//
#include <hip/hip_runtime.h>

// VQ codebook assignment via split-f16 MFMA GEMM — LDS-E (K-halved), barrier-light, high-occupancy.
//   x:       [B=32, C=256, H=32, W=32] f32   -> tokens [32768][256]
//   embed_w: [K=2048, C=256] f32
// out f32: quantize [32,256,32,32] (8388608) | embed_index [32,32,32] (32768 as float) | loss [1]=0
//
// Math (verified R2-R7): e' = 8192*e; eh=f16(e'), el=f16((e'-eh)*4096); xh=f16(x), xl=f16((x-xh)*4096).
//   8192*dot = acc1 + acc2/4096,  acc1 = sum xh*eh, acc2 = sum(xh*el + xl*eh)
//   d' = 8192*esq - 2*acc1 - 2^-11*acc2 ; argmin_k d' == argmin_k (esq - 2 dot)  (err ~2^-24 rel)
//
// R8 design from R5-R7 post-mortems: all structures stalled at ~29% MfmaUtil because 64KB
// LDS -> 2 blocks/CU -> no TLP to cover L2 latency + epilogue tails. Now: E staged in TWO
// 32KB K-halves (2 extra barriers) -> 32KB LDS -> ~5 blocks/CU (20 waves). A-frags are
// nontemporal (zero reuse; don't pollute L1). R3: no global_load_lds. R4: regs never capped
// below need (244 < 512 at min-4-blocks).
//
// ws fragment-panel layout:
//   A: [panel 512][kc 8][limb 2][slot 4][row 64][16B]  = 32 MB   (64 tokens/panel)
//   E: [panel 32 ][kc 8][limb 2][slot 4][row 64][16B]  =  2 MB   (64 codes/panel)

#define CDIM 256
#define KDIM 2048
#define HW   1024
#define NTOK 32768
#define QOFF 8388608
#define LOFF (QOFF + NTOK)

typedef _Float16 f16x8 __attribute__((ext_vector_type(8)));
typedef float    f32x4 __attribute__((ext_vector_type(4)));

__device__ __forceinline__ f16x8 ld16(const char* p) { return *(const f16x8*)(p); }
__device__ __forceinline__ f16x8 ld16nt(const char* p) {
    return __builtin_nontemporal_load((const f16x8*)(p));
}

// ---------------- prep E: limbs into fragment panels + scaled esq + loss ----------------
__global__ __launch_bounds__(256) void prep_e_kernel(const float* __restrict__ ew,
                                                     char* __restrict__ Ews,
                                                     float* __restrict__ esq,
                                                     float* __restrict__ out) {
    const int t = threadIdx.x;
    const int code = blockIdx.x * 8 + (t >> 5);   // 256 blocks x 8 codes
    const int u = t & 31;                          // 8-channel unit: channels u*8..u*8+7
    const float4 v0 = *(const float4*)&ew[(size_t)code * CDIM + u * 8];
    const float4 v1 = *(const float4*)&ew[(size_t)code * CDIM + u * 8 + 4];
    float s = v0.x*v0.x + v0.y*v0.y + v0.z*v0.z + v0.w*v0.w
            + v1.x*v1.x + v1.y*v1.y + v1.z*v1.z + v1.w*v1.w;
    #pragma unroll
    for (int m = 16; m >= 1; m >>= 1) s += __shfl_xor(s, m, 32);
    if (u == 0) esq[code] = s * 8192.0f;
    const float e[8] = {v0.x, v0.y, v0.z, v0.w, v1.x, v1.y, v1.z, v1.w};
    union { _Float16 h[8]; uint4 q; } H, L;
    #pragma unroll
    for (int j = 0; j < 8; ++j) {
        const float ev = e[j] * 8192.0f;
        const _Float16 hh = (_Float16)ev;
        H.h[j] = hh;
        L.h[j] = (_Float16)((ev - (float)hh) * 4096.0f);
    }
    const int kc = u >> 2, g = u & 3;
    const int p = code >> 6, row = code & 63;
    char* d = Ews + (size_t)p * 65536 + kc * 8192 + g * 1024 + row * 16;
    *(uint4*)d = H.q;              // high limb
    *(uint4*)(d + 4096) = L.q;     // low limb
    if (blockIdx.x == 0 && t == 0) out[LOFF] = 0.0f;
}

// ---------------- prep X: transpose [C][HW] -> fragment panels ----------------
__global__ __launch_bounds__(256) void prep_x_kernel(const float* __restrict__ x,
                                                     char* __restrict__ Aws) {
    __shared__ float tile[32][257];
    const int bid = blockIdx.x;              // 32 b * 8 kc * 4 hwblk = 1024
    const int b = bid >> 5;
    const int kc = (bid >> 2) & 7;
    const int c0 = kc * 32;
    const int hw0 = (bid & 3) * 256;
    const int t = threadIdx.x;
    #pragma unroll 8
    for (int r = 0; r < 32; ++r)
        tile[r][t] = x[((size_t)(b * CDIM + c0 + r) << 10) + hw0 + t];
    __syncthreads();
    union { _Float16 h[32]; uint4 q[4]; } Hb, Lb;
    #pragma unroll 8
    for (int r = 0; r < 32; ++r) {
        const float xv = tile[r][t];
        const _Float16 hh = (_Float16)xv;
        Hb.h[r] = hh;
        Lb.h[r] = (_Float16)((xv - (float)hh) * 4096.0f);
    }
    const int tok = b * HW + hw0 + t;
    const int p = tok >> 6, row = tok & 63;
    char* d = Aws + (size_t)p * 65536 + kc * 8192 + row * 16;
    #pragma unroll
    for (int g = 0; g < 4; ++g) {
        *(uint4*)(d + g * 1024)        = Hb.q[g];   // high limb
        *(uint4*)(d + 4096 + g * 1024) = Lb.q[g];   // low limb
    }
}

// ---------------- fused MFMA GEMM + argmin: 32KB LDS-E, K-halved, high occupancy ----------------
// Block = 4 waves x 64 tokens (256 tokens) over ONE shared 64-code panel.
__global__ __launch_bounds__(256, 4) void vqmm_kernel(const char* __restrict__ Aws,
                                                      const char* __restrict__ Ews,
                                                      const float* __restrict__ esq,
                                                      float* __restrict__ cv,
                                                      int* __restrict__ ci) {
    __shared__ __align__(16) char elds[32768];   // one K-half: [kc 4][limb 2][slot 4][code 64][16B]

    const int t = threadIdx.x;
    const int bid = blockIdx.x;
    // bijective XCD-grouped swizzle: all 32 code-panels of one token-group share bid%8
    const int by = (bid & 7) | ((bid >> 8) << 3);   // token group 0..127 (256 tokens)
    const int bx = (bid >> 3) & 31;                 // code panel 0..31   (64 codes)
    const int lane = t & 63, w = t >> 6;
    const int g = lane >> 4, lr = lane & 15;

    // this wave's 64-token A subpanel
    const char* pa = Aws + (size_t)(by * 4 + w) * 65536 + g * 1024 + lr * 16;
    const char* esrc = Ews + (size_t)bx * 65536;

    f16x8 fa[4], fb[4], ec[2][4], ed[2][4];
    // A frags for kc=0 (issued before LDS staging so they fly early)
    #pragma unroll
    for (int m = 0; m < 4; ++m) {
        fa[m] = ld16nt(pa + m * 256);
        fb[m] = ld16nt(pa + 4096 + m * 256);
    }
    // stage E half-0 (32 KB): 256 threads x 8 x 16B
    #pragma unroll
    for (int j = 0; j < 8; ++j) {
        const int off = j * 4096 + t * 16;
        *(uint4*)(elds + off) = *(const uint4*)(esrc + off);
    }
    __syncthreads();

    const f32x4 zf = {0.f, 0.f, 0.f, 0.f};
    f32x4 acc1[4][4], acc2[4][4];
    #pragma unroll
    for (int m = 0; m < 4; ++m)
        #pragma unroll
        for (int n = 0; n < 4; ++n) { acc1[m][n] = zf; acc2[m][n] = zf; }

    const char* el0 = elds + g * 1024 + lr * 16;   // lane's E-frag base within half
    // E frags for kc=0
    #pragma unroll
    for (int n = 0; n < 4; ++n) {
        ec[0][n] = ld16(el0 + n * 256);
        ed[0][n] = ld16(el0 + 4096 + n * 256);
    }

    #pragma unroll
    for (int h = 0; h < 2; ++h) {
        if (h == 1) {
            __syncthreads();   // all waves done reading half-0
            #pragma unroll
            for (int j = 0; j < 8; ++j) {
                const int off = j * 4096 + t * 16;
                *(uint4*)(elds + off) = *(const uint4*)(esrc + 32768 + off);
            }
            __syncthreads();   // half-1 visible
            // E frags for kc=4 (latency exposed once; hidden by other blocks)
            #pragma unroll
            for (int n = 0; n < 4; ++n) {
                ec[0][n] = ld16(el0 + n * 256);
                ed[0][n] = ld16(el0 + 4096 + n * 256);
            }
        }
        #pragma unroll
        for (int kci = 0; kci < 4; ++kci) {
            const int kc = h * 4 + kci;
            const int cur = kci & 1, nxt = cur ^ 1;
            // E prefetch for next kc within this half (covered by this phase's 48 MFMAs)
            if (kci < 3) {
                const char* en = el0 + (kci + 1) * 8192;
                #pragma unroll
                for (int n = 0; n < 4; ++n) {
                    ec[nxt][n] = ld16(en + n * 256);
                    ed[nxt][n] = ld16(en + 4096 + n * 256);
                }
            }
            const char* pan = pa + (kc + 1) * 8192;
            #pragma unroll
            for (int m = 0; m < 4; ++m) {
                #pragma unroll
                for (int n = 0; n < 4; ++n) {
                    acc1[m][n] = __builtin_amdgcn_mfma_f32_16x16x32_f16(fa[m], ec[cur][n], acc1[m][n], 0, 0, 0);
                    acc2[m][n] = __builtin_amdgcn_mfma_f32_16x16x32_f16(fa[m], ed[cur][n], acc2[m][n], 0, 0, 0);
                    acc2[m][n] = __builtin_amdgcn_mfma_f32_16x16x32_f16(fb[m], ec[cur][n], acc2[m][n], 0, 0, 0);
                }
                // A reload for kc+1 right after fa[m]/fb[m]'s last use
                if (kc < 7) {
                    fa[m] = ld16nt(pan + m * 256);
                    fb[m] = ld16nt(pan + 4096 + m * 256);
                }
            }
            // kci==3,h==0: ec[0] (cur for kc=4) is reloaded after restage above
        }
    }

    // epilogue: per-wave argmin over its 64 codes; waves own disjoint tokens -> no merge
    float eq[4];
    #pragma unroll
    for (int n = 0; n < 4; ++n) eq[n] = esq[bx * 64 + n * 16 + lr];
    #pragma unroll
    for (int m = 0; m < 4; ++m) {
        #pragma unroll
        for (int r = 0; r < 4; ++r) {
            float bv = 3.4e38f; int bi = 0x7fffffff;
            #pragma unroll
            for (int n = 0; n < 4; ++n) {
                const float d = fmaf(-2.0f, acc1[m][n][r],
                                fmaf(-4.8828125e-4f, acc2[m][n][r], eq[n]));
                const int cidx = bx * 64 + n * 16 + lr;
                if (d < bv) { bv = d; bi = cidx; }
            }
            #pragma unroll
            for (int mk = 1; mk < 16; mk <<= 1) {
                const float ov = __shfl_xor(bv, mk, 16);
                const int   oi = __shfl_xor(bi, mk, 16);
                if (ov < bv || (ov == bv && oi < bi)) { bv = ov; bi = oi; }
            }
            if (lr == 0) {
                const size_t o = (size_t)bx * NTOK + by * 256 + w * 64 + m * 16 + g * 4 + r;
                cv[o] = bv; ci[o] = bi;
            }
        }
    }
}

// ---------------- merge 32 candidates + gather quantize ----------------
__global__ __launch_bounds__(256) void merge_gather_kernel(const float* __restrict__ cv,
                                                           const int* __restrict__ ci,
                                                           const float* __restrict__ ew,
                                                           float* __restrict__ out) {
    __shared__ int sIdx[64];
    const int t = threadIdx.x;
    const int n0 = blockIdx.x * 64;
    if (t < 64) {
        const int tok = n0 + t;
        float bv = cv[tok]; int bi = ci[tok];
        #pragma unroll
        for (int s = 1; s < 32; ++s) {
            const float v = cv[(size_t)s * NTOK + tok];
            const int   i2 = ci[(size_t)s * NTOK + tok];
            if (v < bv || (v == bv && i2 < bi)) { bv = v; bi = i2; }
        }
        sIdx[t] = bi;
        out[QOFF + tok] = (float)bi;
    }
    __syncthreads();
    const int b = n0 >> 10, hw0 = n0 & (HW - 1);
    const int i = t & 63, cg = t >> 6;
    const int kidx = sIdx[i];
    const float* er = ew + (size_t)kidx * CDIM;
    float* ob = out + (size_t)b * CDIM * HW + hw0 + i;
    #pragma unroll
    for (int p = 0; p < CDIM / 4; ++p) {
        const int c = cg * 64 + p;
        ob[(size_t)c * HW] = er[c];
    }
}

extern "C" void kernel_launch(void* const* d_in, const int* in_sizes, int n_in,
                              void* d_out, int out_size, void* d_ws, size_t ws_size,
                              hipStream_t stream) {
    const float* x  = (const float*)d_in[0];
    const float* ew = (const float*)d_in[1];
    float* out = (float*)d_out;
    char* ws = (char*)d_ws;

    char*  Aws = ws;                                // 33,554,432 B
    char*  Ews = ws + 33554432;                     //  2,097,152 B
    float* esq = (float*)(ws + 35651584);           //      8,192 B
    float* cvv = (float*)(ws + 35659776);           //  4,194,304 B (32 sets)
    int*   cii = (int*)(ws + 39854080);             //  4,194,304 B

    prep_e_kernel<<<KDIM / 8, 256, 0, stream>>>(ew, Ews, esq, out);
    prep_x_kernel<<<1024, 256, 0, stream>>>(x, Aws);
    vqmm_kernel<<<4096, 256, 0, stream>>>(Aws, Ews, esq, cvv, cii);
    merge_gather_kernel<<<NTOK / 64, 256, 0, stream>>>(cvv, cii, ew, out);
}

// Round 9
// 169.876 us; speedup vs baseline: 6.7774x; 6.7774x over previous
//
#include <hip/hip_runtime.h>

// VQ codebook assignment via split-f16 MFMA GEMM — LDS-resident E, barrier-free K-loop,
// per-wave K-phase rotation (anti-lockstep) + setprio MFMA clusters.
//   x:       [B=32, C=256, H=32, W=32] f32   -> tokens [32768][256]
//   embed_w: [K=2048, C=256] f32
// out f32: quantize [32,256,32,32] (8388608) | embed_index [32,32,32] (32768 as float) | loss [1]=0
//
// Math (verified R2-R8): e' = 8192*e; eh=f16(e'), el=f16((e'-eh)*4096); xh=f16(x), xl=f16((x-xh)*4096).
//   8192*dot = acc1 + acc2/4096,  acc1 = sum xh*eh, acc2 = sum(xh*el + xl*eh)
//   d' = 8192*esq - 2*acc1 - 2^-11*acc2 ; argmin_k d' == argmin_k (esq - 2 dot)  (err ~2^-24 rel;
//   kc-rotation reorders f32 accumulation — rounding shift ~1e-7, 50x below argmin margin)
//
// R9 changes vs R7 (146us, MfmaUtil 29%): co-resident waves ran lockstep -> simultaneous
// load bursts starved the matrix pipe. Now each wave starts K at kc0=(2*(bid+w))&7 and
// MFMA nests run at priority 1. R3: no global_load_lds. R4/R8: regs need ~244 -> never
// request >2 waves/SIMD.
//
// ws fragment-panel layout:
//   A: [panel 512][kc 8][limb 2][slot 4][row 64][16B]  = 32 MB   (64 tokens/panel)
//   E: [panel 32 ][kc 8][limb 2][slot 4][row 64][16B]  =  2 MB   (64 codes/panel)

#define CDIM 256
#define KDIM 2048
#define HW   1024
#define NTOK 32768
#define QOFF 8388608
#define LOFF (QOFF + NTOK)

typedef _Float16 f16x8 __attribute__((ext_vector_type(8)));
typedef float    f32x4 __attribute__((ext_vector_type(4)));

__device__ __forceinline__ f16x8 ld16(const char* p) { return *(const f16x8*)(p); }
__device__ __forceinline__ f16x8 ld16nt(const char* p) {
    return __builtin_nontemporal_load((const f16x8*)(p));
}

// ---------------- prep E: limbs into fragment panels + scaled esq + loss ----------------
__global__ __launch_bounds__(256) void prep_e_kernel(const float* __restrict__ ew,
                                                     char* __restrict__ Ews,
                                                     float* __restrict__ esq,
                                                     float* __restrict__ out) {
    const int t = threadIdx.x;
    const int code = blockIdx.x * 8 + (t >> 5);   // 256 blocks x 8 codes
    const int u = t & 31;                          // 8-channel unit: channels u*8..u*8+7
    const float4 v0 = *(const float4*)&ew[(size_t)code * CDIM + u * 8];
    const float4 v1 = *(const float4*)&ew[(size_t)code * CDIM + u * 8 + 4];
    float s = v0.x*v0.x + v0.y*v0.y + v0.z*v0.z + v0.w*v0.w
            + v1.x*v1.x + v1.y*v1.y + v1.z*v1.z + v1.w*v1.w;
    #pragma unroll
    for (int m = 16; m >= 1; m >>= 1) s += __shfl_xor(s, m, 32);
    if (u == 0) esq[code] = s * 8192.0f;
    const float e[8] = {v0.x, v0.y, v0.z, v0.w, v1.x, v1.y, v1.z, v1.w};
    union { _Float16 h[8]; uint4 q; } H, L;
    #pragma unroll
    for (int j = 0; j < 8; ++j) {
        const float ev = e[j] * 8192.0f;
        const _Float16 hh = (_Float16)ev;
        H.h[j] = hh;
        L.h[j] = (_Float16)((ev - (float)hh) * 4096.0f);
    }
    const int kc = u >> 2, g = u & 3;
    const int p = code >> 6, row = code & 63;
    char* d = Ews + (size_t)p * 65536 + kc * 8192 + g * 1024 + row * 16;
    *(uint4*)d = H.q;              // high limb
    *(uint4*)(d + 4096) = L.q;     // low limb
    if (blockIdx.x == 0 && t == 0) out[LOFF] = 0.0f;
}

// ---------------- prep X: transpose [C][HW] -> fragment panels ----------------
__global__ __launch_bounds__(256) void prep_x_kernel(const float* __restrict__ x,
                                                     char* __restrict__ Aws) {
    __shared__ float tile[32][257];
    const int bid = blockIdx.x;              // 32 b * 8 kc * 4 hwblk = 1024
    const int b = bid >> 5;
    const int kc = (bid >> 2) & 7;
    const int c0 = kc * 32;
    const int hw0 = (bid & 3) * 256;
    const int t = threadIdx.x;
    #pragma unroll 8
    for (int r = 0; r < 32; ++r)
        tile[r][t] = x[((size_t)(b * CDIM + c0 + r) << 10) + hw0 + t];
    __syncthreads();
    union { _Float16 h[32]; uint4 q[4]; } Hb, Lb;
    #pragma unroll 8
    for (int r = 0; r < 32; ++r) {
        const float xv = tile[r][t];
        const _Float16 hh = (_Float16)xv;
        Hb.h[r] = hh;
        Lb.h[r] = (_Float16)((xv - (float)hh) * 4096.0f);
    }
    const int tok = b * HW + hw0 + t;
    const int p = tok >> 6, row = tok & 63;
    char* d = Aws + (size_t)p * 65536 + kc * 8192 + row * 16;
    #pragma unroll
    for (int g = 0; g < 4; ++g) {
        *(uint4*)(d + g * 1024)        = Hb.q[g];   // high limb
        *(uint4*)(d + 4096 + g * 1024) = Lb.q[g];   // low limb
    }
}

// ---------------- fused MFMA GEMM + argmin: LDS-E, rotated barrier-free K-loop ----------------
// Block = 4 waves x 64 tokens (256 tokens) over ONE shared 64-code panel in LDS.
__global__ __launch_bounds__(256, 2) void vqmm_kernel(const char* __restrict__ Aws,
                                                      const char* __restrict__ Ews,
                                                      const float* __restrict__ esq,
                                                      float* __restrict__ cv,
                                                      int* __restrict__ ci) {
    __shared__ __align__(16) char elds[65536];   // [kc 8][limb 2][slot 4][code 64][16B]

    const int t = threadIdx.x;
    const int bid = blockIdx.x;
    // bijective XCD-grouped swizzle: all 32 code-panels of one token-group share bid%8
    const int by = (bid & 7) | ((bid >> 8) << 3);   // token group 0..127 (256 tokens)
    const int bx = (bid >> 3) & 31;                 // code panel 0..31   (64 codes)
    const int lane = t & 63, w = t >> 6;
    const int g = lane >> 4, lr = lane & 15;
    const int kc0 = (2 * (bid + w)) & 7;            // per-wave phase rotation (anti-lockstep)

    // this wave's 64-token A subpanel
    const char* pa = Aws + (size_t)(by * 4 + w) * 65536 + g * 1024 + lr * 16;

    // stage E panel (64 KB) into LDS: 256 threads x 16 x 16B, linear copy
    {
        const char* esrc = Ews + (size_t)bx * 65536;
        #pragma unroll
        for (int j = 0; j < 16; ++j) {
            const int off = j * 4096 + t * 16;
            *(uint4*)(elds + off) = *(const uint4*)(esrc + off);
        }
    }

    f16x8 fa[4], fb[4], ec[2][4], ed[2][4];
    // A frags for first phase (kc0)
    {
        const char* pa0 = pa + kc0 * 8192;
        #pragma unroll
        for (int m = 0; m < 4; ++m) {
            fa[m] = ld16nt(pa0 + m * 256);
            fb[m] = ld16nt(pa0 + 4096 + m * 256);
        }
    }
    __syncthreads();   // the only block-wide barrier

    const f32x4 zf = {0.f, 0.f, 0.f, 0.f};
    f32x4 acc1[4][4], acc2[4][4];
    #pragma unroll
    for (int m = 0; m < 4; ++m)
        #pragma unroll
        for (int n = 0; n < 4; ++n) { acc1[m][n] = zf; acc2[m][n] = zf; }

    const char* el0 = elds + g * 1024 + lr * 16;   // lane's E-frag base
    // E frags for first phase (LDS)
    {
        const char* ep0 = el0 + kc0 * 8192;
        #pragma unroll
        for (int n = 0; n < 4; ++n) {
            ec[0][n] = ld16(ep0 + n * 256);
            ed[0][n] = ld16(ep0 + 4096 + n * 256);
        }
    }

    #pragma unroll
    for (int i = 0; i < 8; ++i) {
        const int cur = i & 1, nxt = cur ^ 1;
        const int kcn = (kc0 + i + 1) & 7;          // next phase's K-chunk (wave-uniform)
        // E prefetch for next phase from LDS (covered by this phase's 48 MFMAs)
        if (i < 7) {
            const char* en = el0 + kcn * 8192;
            #pragma unroll
            for (int n = 0; n < 4; ++n) {
                ec[nxt][n] = ld16(en + n * 256);
                ed[nxt][n] = ld16(en + 4096 + n * 256);
            }
        }
        const char* pan = pa + kcn * 8192;
        #pragma unroll
        for (int m = 0; m < 4; ++m) {
            __builtin_amdgcn_s_setprio(1);
            #pragma unroll
            for (int n = 0; n < 4; ++n) {
                acc1[m][n] = __builtin_amdgcn_mfma_f32_16x16x32_f16(fa[m], ec[cur][n], acc1[m][n], 0, 0, 0);
                acc2[m][n] = __builtin_amdgcn_mfma_f32_16x16x32_f16(fa[m], ed[cur][n], acc2[m][n], 0, 0, 0);
                acc2[m][n] = __builtin_amdgcn_mfma_f32_16x16x32_f16(fb[m], ec[cur][n], acc2[m][n], 0, 0, 0);
            }
            __builtin_amdgcn_s_setprio(0);
            // A reload for next phase right after fa[m]/fb[m]'s last use
            if (i < 7) {
                fa[m] = ld16nt(pan + m * 256);
                fb[m] = ld16nt(pan + 4096 + m * 256);
            }
        }
    }

    // epilogue: per-wave argmin over its 64 codes; waves own disjoint tokens -> no merge
    float eq[4];
    #pragma unroll
    for (int n = 0; n < 4; ++n) eq[n] = esq[bx * 64 + n * 16 + lr];
    #pragma unroll
    for (int m = 0; m < 4; ++m) {
        #pragma unroll
        for (int r = 0; r < 4; ++r) {
            float bv = 3.4e38f; int bi = 0x7fffffff;
            #pragma unroll
            for (int n = 0; n < 4; ++n) {
                const float d = fmaf(-2.0f, acc1[m][n][r],
                                fmaf(-4.8828125e-4f, acc2[m][n][r], eq[n]));
                const int cidx = bx * 64 + n * 16 + lr;
                if (d < bv) { bv = d; bi = cidx; }
            }
            #pragma unroll
            for (int mk = 1; mk < 16; mk <<= 1) {
                const float ov = __shfl_xor(bv, mk, 16);
                const int   oi = __shfl_xor(bi, mk, 16);
                if (ov < bv || (ov == bv && oi < bi)) { bv = ov; bi = oi; }
            }
            if (lr == 0) {
                const size_t o = (size_t)bx * NTOK + by * 256 + w * 64 + m * 16 + g * 4 + r;
                cv[o] = bv; ci[o] = bi;
            }
        }
    }
}

// ---------------- merge 32 candidates + gather quantize ----------------
__global__ __launch_bounds__(256) void merge_gather_kernel(const float* __restrict__ cv,
                                                           const int* __restrict__ ci,
                                                           const float* __restrict__ ew,
                                                           float* __restrict__ out) {
    __shared__ int sIdx[64];
    const int t = threadIdx.x;
    const int n0 = blockIdx.x * 64;
    if (t < 64) {
        const int tok = n0 + t;
        float bv = cv[tok]; int bi = ci[tok];
        #pragma unroll
        for (int s = 1; s < 32; ++s) {
            const float v = cv[(size_t)s * NTOK + tok];
            const int   i2 = ci[(size_t)s * NTOK + tok];
            if (v < bv || (v == bv && i2 < bi)) { bv = v; bi = i2; }
        }
        sIdx[t] = bi;
        out[QOFF + tok] = (float)bi;
    }
    __syncthreads();
    const int b = n0 >> 10, hw0 = n0 & (HW - 1);
    const int i = t & 63, cg = t >> 6;
    const int kidx = sIdx[i];
    const float* er = ew + (size_t)kidx * CDIM;
    float* ob = out + (size_t)b * CDIM * HW + hw0 + i;
    #pragma unroll
    for (int p = 0; p < CDIM / 4; ++p) {
        const int c = cg * 64 + p;
        ob[(size_t)c * HW] = er[c];
    }
}

extern "C" void kernel_launch(void* const* d_in, const int* in_sizes, int n_in,
                              void* d_out, int out_size, void* d_ws, size_t ws_size,
                              hipStream_t stream) {
    const float* x  = (const float*)d_in[0];
    const float* ew = (const float*)d_in[1];
    float* out = (float*)d_out;
    char* ws = (char*)d_ws;

    char*  Aws = ws;                                // 33,554,432 B
    char*  Ews = ws + 33554432;                     //  2,097,152 B
    float* esq = (float*)(ws + 35651584);           //      8,192 B
    float* cvv = (float*)(ws + 35659776);           //  4,194,304 B (32 sets)
    int*   cii = (int*)(ws + 39854080);             //  4,194,304 B

    prep_e_kernel<<<KDIM / 8, 256, 0, stream>>>(ew, Ews, esq, out);
    prep_x_kernel<<<1024, 256, 0, stream>>>(x, Aws);
    vqmm_kernel<<<4096, 256, 0, stream>>>(Aws, Ews, esq, cvv, cii);
    merge_gather_kernel<<<NTOK / 64, 256, 0, stream>>>(cvv, cii, ew, out);
}